// Round 1
// baseline (104.491 us; speedup 1.0000x reference)
//
#include <hip/hip_runtime.h>

// Inverse dyadic wavelet synthesis step (db4, circular boundary).
// out[r][2s]   = sum_{i=0..3} d[r][(s+i)%M]*g[2i]   + a[r][(s+i)%M]*h[2i]
// out[r][2s+1] = sum_{i=1..4} d[r][(s+i)%M]*g[2i-1] + a[r][(s+i)%M]*h[2i-1]
// h = scaling, g[k] = scaling[7-k] * (-1)^k
//
// Memory-bound: 256 MiB in + 256 MiB out -> target ~81 us @ 6.3 TB/s.

#define M_LEN 8192
#define N_ROWS 4096
#define THREADS_PER_ROW (M_LEN / 4)   // each thread covers 4 s-values -> 8 outputs

__global__ __launch_bounds__(256) void idwt_db4_kernel(
    const float* __restrict__ det,
    const float* __restrict__ apx,
    const float* __restrict__ sc,
    float* __restrict__ out)
{
    const int gid = blockIdx.x * 256 + threadIdx.x;
    const int row = gid >> 11;               // gid / THREADS_PER_ROW (2048)
    const int s0  = (gid & 2047) << 2;       // first s handled by this thread

    // load filter (uniform address -> scalar loads, L2-hit broadcast)
    const float h0 = sc[0], h1 = sc[1], h2 = sc[2], h3 = sc[3];
    const float h4 = sc[4], h5 = sc[5], h6 = sc[6], h7 = sc[7];
    // g[k] = sc[7-k] * ((k & 1) ? -1 : 1)
    const float g0 =  h7, g1 = -h6, g2 =  h5, g3 = -h4;
    const float g4 =  h3, g5 = -h2, g6 =  h1, g7 = -h0;

    const float* __restrict__ dr = det + (size_t)row * M_LEN;
    const float* __restrict__ ar = apx + (size_t)row * M_LEN;

    float d[8], a[8];
    if (s0 + 8 <= M_LEN) {
        // fast path: two aligned float4 loads per input
        const float4 dv0 = *(const float4*)(dr + s0);
        const float4 dv1 = *(const float4*)(dr + s0 + 4);
        const float4 av0 = *(const float4*)(ar + s0);
        const float4 av1 = *(const float4*)(ar + s0 + 4);
        d[0] = dv0.x; d[1] = dv0.y; d[2] = dv0.z; d[3] = dv0.w;
        d[4] = dv1.x; d[5] = dv1.y; d[6] = dv1.z; d[7] = dv1.w;
        a[0] = av0.x; a[1] = av0.y; a[2] = av0.z; a[3] = av0.w;
        a[4] = av1.x; a[5] = av1.y; a[6] = av1.z; a[7] = av1.w;
    } else {
        // circular wrap: only the last thread of each row (1 lane / 2048)
#pragma unroll
        for (int i = 0; i < 8; ++i) {
            const int idx = (s0 + i) & (M_LEN - 1);
            d[i] = dr[idx];
            a[i] = ar[idx];
        }
    }

    float o[8];
#pragma unroll
    for (int k = 0; k < 4; ++k) {
        o[2*k]     = d[k]  * g0 + d[k+1] * g2 + d[k+2] * g4 + d[k+3] * g6
                   + a[k]  * h0 + a[k+1] * h2 + a[k+2] * h4 + a[k+3] * h6;
        o[2*k + 1] = d[k+1] * g1 + d[k+2] * g3 + d[k+3] * g5 + d[k+4] * g7
                   + a[k+1] * h1 + a[k+2] * h3 + a[k+3] * h5 + a[k+4] * h7;
    }

    float* __restrict__ orow = out + (size_t)row * (2 * M_LEN) + 2 * s0;
    *(float4*)(orow)     = make_float4(o[0], o[1], o[2], o[3]);
    *(float4*)(orow + 4) = make_float4(o[4], o[5], o[6], o[7]);
}

extern "C" void kernel_launch(void* const* d_in, const int* in_sizes, int n_in,
                              void* d_out, int out_size, void* d_ws, size_t ws_size,
                              hipStream_t stream) {
    const float* det = (const float*)d_in[0];   // details      (4096, 8192) f32
    const float* apx = (const float*)d_in[1];   // approximation(4096, 8192) f32
    const float* sc  = (const float*)d_in[2];   // scaling      (8,)         f32
    float* out = (float*)d_out;                 // (4096, 16384) f32

    const int total_threads = N_ROWS * THREADS_PER_ROW;   // 8,388,608
    const int blocks = total_threads / 256;                // 32,768

    idwt_db4_kernel<<<blocks, 256, 0, stream>>>(det, apx, sc, out);
}